// Round 15
// baseline (89.183 us; speedup 1.0000x reference)
//
#include <hip/hip_runtime.h>
#include <hip/hip_bf16.h>
#include <math.h>

// Problem constants (from the reference)
#define BB 512        // batch
#define CC 1000       // classes
#define TT 64         // num param tensors
#define PSZ 500000    // elements per tensor
#define NW 9          // loss weights per tensor

// Param decomposition (R7 structure, proven best: ~72us fused / 77.6us total):
// 10 blocks per tensor, contiguous chunks of 12500 float4.
// 12500 = 3*4096 + 212 -> 3 bursts of (16 x 256 float4 = 64 KB) + tail.
// TAIL4 = 212 < 256: single-pass tail guard correct.
#define BPT 10
#define PBLKS (TT * BPT)   // 640
#define C4 12500
#define TAIL4 212
#define NBLOCKS (PBLKS + BB)   // 1152

// Workspace layout (floats):
//  ws[0] = sum_b CE contribution    ws[1] = sum_b hinge row sums
//  ws[2] = sum_{b,j} logp           ws[3] = sum_b sum_j p*logp
//  ws[4] = sum_{b,j} o^2
//  ws_u32[6] = completion counter (zeroed by launch memset)
//  ws[8 + t*4 + {0,1,2,3}] = {l1_zero, sumsq_zero, l1_pre, sumsq_pre}
#define WS_FLOATS (8 + TT * 4)
#define CTR_IDX 6

typedef float f32x4 __attribute__((ext_vector_type(4)));

__device__ __forceinline__ f32x4 ntload(const f32x4* a) {
    return __builtin_nontemporal_load(a);
}

// agent-scope atomic load: reads the device coherence point (bypasses stale
// L1/L2) — proven correct in R13's combine, without R13's threadfence cost.
__device__ __forceinline__ float aload(const float* p) {
    return __hip_atomic_load(p, __ATOMIC_RELAXED, __HIP_MEMORY_SCOPE_AGENT);
}

// ---------------------------------------------------------------------------
__device__ __forceinline__ float block_reduce_sum(float v, float* scratch) {
    __syncthreads();
    for (int o = 32; o > 0; o >>= 1) v += __shfl_down(v, o);
    const int wave = threadIdx.x >> 6;
    if ((threadIdx.x & 63) == 0) scratch[wave] = v;
    __syncthreads();
    return scratch[0] + scratch[1] + scratch[2] + scratch[3];
}

__device__ __forceinline__ float block_reduce_max(float v, float* scratch) {
    __syncthreads();
    for (int o = 32; o > 0; o >>= 1) v = fmaxf(v, __shfl_down(v, o));
    const int wave = threadIdx.x >> 6;
    if ((threadIdx.x & 63) == 0) scratch[wave] = v;
    __syncthreads();
    return fmaxf(fmaxf(scratch[0], scratch[1]), fmaxf(scratch[2], scratch[3]));
}

__device__ __forceinline__ void acc4(const f32x4 a, const f32x4 c,
                                     float& l1z, float& s2z,
                                     float& l1p, float& s2p) {
    l1z += fabsf(a.x) + fabsf(a.y) + fabsf(a.z) + fabsf(a.w);
    s2z += a.x * a.x + a.y * a.y + a.z * a.z + a.w * a.w;
    const float dx = a.x - c.x, dy = a.y - c.y, dz = a.z - c.z, dw = a.w - c.w;
    l1p += fabsf(dx) + fabsf(dy) + fabsf(dz) + fabsf(dw);
    s2p += dx * dx + dy * dy + dz * dz + dw * dw;
}

// ---------------------------------------------------------------------------
// Fused kernel — EXACT R7 param/logits structure + fence-free last-block
// combine. Ordering argument: every partial is a device-coherent atomicAdd;
// each block drains its own atomics with s_waitcnt vmcnt(0) (cheap: own-queue
// ack drain, no L2 writeback) BEFORE its counter add, so when the last block
// sees counter == NBLOCKS-1, all partials are at the coherence point; it
// reads them with agent-scope atomic loads. R13's 1152x __threadfence()
// (L2 writeback per block) is what cost 3x — not the fold itself.
// ---------------------------------------------------------------------------
__global__ __launch_bounds__(256, 2) void fused_kernel(
        const float* __restrict__ p, const float* __restrict__ q,
        const float* __restrict__ outlog, const int* __restrict__ tgt,
        const float* __restrict__ lw, float* __restrict__ ws,
        float* __restrict__ out) {
    __shared__ float row[CC];
    __shared__ float scratch[4];
    __shared__ int sdone;

    const int bid = blockIdx.x;
    const int tid = (int)threadIdx.x;
    if (bid < PBLKS) {
        // ---------------- param-norm path (256 MB total) -------------------
        const int t = bid / BPT;
        const f32x4* __restrict__ pb = (const f32x4*)p + (long long)bid * C4;
        const f32x4* __restrict__ qb = (const f32x4*)q + (long long)bid * C4;

        float l1z = 0.f, s2z = 0.f, l1p = 0.f, s2p = 0.f;

        #pragma unroll 1
        for (int j = 0; j < 3; ++j) {
            const f32x4* bp = pb + j * 4096 + tid;
            const f32x4* bq = qb + j * 4096 + tid;
            f32x4 A[16];
            #pragma unroll
            for (int k = 0; k < 16; ++k) A[k] = ntload(bp + k * 256);
            #pragma unroll
            for (int g = 0; g < 4; ++g) {
                f32x4 Cg[4];
                #pragma unroll
                for (int k = 0; k < 4; ++k) Cg[k] = ntload(bq + (g * 4 + k) * 256);
                #pragma unroll
                for (int k = 0; k < 4; ++k)
                    acc4(A[g * 4 + k], Cg[k], l1z, s2z, l1p, s2p);
            }
        }
        // tail: 212 float4 at chunk offset 12288 (212 < 256: single pass OK)
        if (tid < TAIL4) {
            const f32x4 a = ntload(pb + 3 * 4096 + tid);
            const f32x4 c = ntload(qb + 3 * 4096 + tid);
            acc4(a, c, l1z, s2z, l1p, s2p);
        }

        for (int o = 32; o > 0; o >>= 1) {
            l1z += __shfl_down(l1z, o);
            s2z += __shfl_down(s2z, o);
            l1p += __shfl_down(l1p, o);
            s2p += __shfl_down(s2p, o);
        }
        if ((tid & 63) == 0) {
            float* base = ws + 8 + t * 4;
            atomicAdd(base + 0, l1z);
            atomicAdd(base + 1, s2z);
            atomicAdd(base + 2, l1p);
            atomicAdd(base + 3, s2p);
        }
    } else {
        // ---------------- logits path (one block per batch row) ------------
        const int b = bid - PBLKS;
        const float* __restrict__ o = outlog + (long long)b * CC;

        float sq = 0.f;
        for (int j = tid; j < CC; j += 256) {
            const float v = o[j];
            row[j] = v;
            sq += v * v;
        }
        __syncthreads();

        float m = -3.402823466e+38f;
        for (int j = tid; j < CC; j += 256) m = fmaxf(m, row[j]);
        m = block_reduce_max(m, scratch);

        float se = 0.f;
        for (int j = tid; j < CC; j += 256) se += __expf(row[j] - m);
        se = block_reduce_sum(se, scratch);
        const float logZ = m + __logf(se);

        const int tg = tgt[b];
        const float ot = row[tg];

        float ent = 0.f, lps = 0.f, hin = 0.f;
        for (int j = tid; j < CC; j += 256) {
            const float lp = row[j] - logZ;
            ent += __expf(lp) * lp;
            lps += lp;
            const float mg = 1.f - ot + row[j];
            if (j != tg && mg > 0.f) hin += mg;
        }
        sq  = block_reduce_sum(sq, scratch);
        ent = block_reduce_sum(ent, scratch);
        lps = block_reduce_sum(lps, scratch);
        hin = block_reduce_sum(hin, scratch);

        if (tid == 0) {
            atomicAdd(&ws[0], -(ot - logZ));
            atomicAdd(&ws[1], hin);
            atomicAdd(&ws[2], lps);
            atomicAdd(&ws[3], ent);
            atomicAdd(&ws[4], sq);
        }
    }

    // ---------------- fence-free last-block combine ------------------------
    if (tid == 0) {
        // drain THIS block's outstanding atomics to the coherence point
        // (cheap own-queue wait; no cross-XCD L2 writeback)
        asm volatile("s_waitcnt vmcnt(0)" ::: "memory");
        unsigned int* ctr = (unsigned int*)ws + CTR_IDX;
        sdone = (int)__hip_atomic_fetch_add(ctr, 1u, __ATOMIC_RELAXED,
                                            __HIP_MEMORY_SCOPE_AGENT);
    }
    __syncthreads();
    if (sdone == NBLOCKS - 1) {
        const float ce      = aload(&ws[0]) / (float)BB;
        const float hinge   = aload(&ws[1]) / ((float)BB * (float)CC);
        const float kl      = -logf((float)CC) - aload(&ws[2]) / ((float)BB * (float)CC);
        const float entropy = -aload(&ws[3]) / (float)BB;
        const float energy  = sqrtf(aload(&ws[4]));
        const float glob[5] = {ce, hinge, kl, entropy, energy};

        float acc = 0.f;
        for (int i = tid; i < TT * NW; i += 256) {
            const int t = i / NW;
            const int k = i - t * NW;
            float cmb;
            if (k < 5)       cmb = glob[k];
            else if (k == 5) cmb = aload(&ws[8 + t * 4 + 0]);
            else if (k == 6) cmb = sqrtf(aload(&ws[8 + t * 4 + 1]));
            else if (k == 7) cmb = aload(&ws[8 + t * 4 + 2]);
            else             cmb = sqrtf(aload(&ws[8 + t * 4 + 3]));
            const float w = 1.f / (1.f + expf(-lw[i]));
            acc += w * cmb;
        }
        acc = block_reduce_sum(acc, scratch);
        if (tid == 0) out[0] = acc / (float)(TT * NW);
    }
}

// ---------------------------------------------------------------------------
extern "C" void kernel_launch(void* const* d_in, const int* in_sizes, int n_in,
                              void* d_out, int out_size, void* d_ws, size_t ws_size,
                              hipStream_t stream) {
    const float* outputs    = (const float*)d_in[0];
    const int*   targets    = (const int*)d_in[1];
    const float* params     = (const float*)d_in[2];
    const float* pretrained = (const float*)d_in[3];
    const float* lw         = (const float*)d_in[4];
    float* ws  = (float*)d_ws;
    float* out = (float*)d_out;

    hipMemsetAsync(ws, 0, WS_FLOATS * sizeof(float), stream);

    // 640 param blocks (64 KB nt runs) + 512 logits blocks; fence-free
    // last-block fold replaces the separate final_kernel launch.
    fused_kernel<<<NBLOCKS, 256, 0, stream>>>(params, pretrained, outputs,
                                              targets, lw, ws, out);
}

// Round 16
// 77.853 us; speedup vs baseline: 1.1455x; 1.1455x over previous
//
#include <hip/hip_runtime.h>
#include <hip/hip_bf16.h>
#include <math.h>

// Problem constants (from the reference)
#define BB 512        // batch
#define CC 1000       // classes
#define TT 64         // num param tensors
#define PSZ 500000    // elements per tensor
#define NW 9          // loss weights per tensor

// Param decomposition (R7 structure — the 15-round empirical optimum):
// 10 blocks per tensor, each a CONTIGUOUS chunk of 12500 float4.
// 12500 = 3 * 4096 + 212 -> 3 bursts of (16 x 256 float4 = 64 KB) + tail.
// TAIL4 = 212 < 256: single-pass tail guard correct.
//
// Measured laws this kernel embodies (rounds 1-15):
//  - 64 KB ascending runs per stream per block: 107 -> 72 us fused (R4->R7);
//    longer runs, XCD windowing, work stealing, lockstep sweeps all <= neutral.
//  - nt loads: +49% on cold passes (R11 A/B).
//  - concurrency/occupancy/residency: no effect (R1-R4).
//  - last-block combine folds (fenced or fence-free): both regress (R13/R15);
//    the separate 1-block final kernel is cheaper.
#define BPT 10
#define PBLKS (TT * BPT)   // 640
#define C4 12500           // float4 per block chunk (chunks tile arrays exactly)
#define TAIL4 212          // 12500 - 3*4096

// Workspace layout (floats):
//  ws[0] = sum_b CE contribution    ws[1] = sum_b hinge row sums
//  ws[2] = sum_{b,j} logp           ws[3] = sum_b sum_j p*logp
//  ws[4] = sum_{b,j} o^2
//  ws[8 + t*4 + {0,1,2,3}] = {l1_zero, sumsq_zero, l1_pre, sumsq_pre}
#define WS_FLOATS (8 + TT * 4)

typedef float f32x4 __attribute__((ext_vector_type(4)));

__device__ __forceinline__ f32x4 ntload(const f32x4* a) {
    return __builtin_nontemporal_load(a);
}

// ---------------------------------------------------------------------------
__device__ __forceinline__ float block_reduce_sum(float v, float* scratch) {
    __syncthreads();
    for (int o = 32; o > 0; o >>= 1) v += __shfl_down(v, o);
    const int wave = threadIdx.x >> 6;
    if ((threadIdx.x & 63) == 0) scratch[wave] = v;
    __syncthreads();
    return scratch[0] + scratch[1] + scratch[2] + scratch[3];
}

__device__ __forceinline__ float block_reduce_max(float v, float* scratch) {
    __syncthreads();
    for (int o = 32; o > 0; o >>= 1) v = fmaxf(v, __shfl_down(v, o));
    const int wave = threadIdx.x >> 6;
    if ((threadIdx.x & 63) == 0) scratch[wave] = v;
    __syncthreads();
    return fmaxf(fmaxf(scratch[0], scratch[1]), fmaxf(scratch[2], scratch[3]));
}

__device__ __forceinline__ void acc4(const f32x4 a, const f32x4 c,
                                     float& l1z, float& s2z,
                                     float& l1p, float& s2p) {
    l1z += fabsf(a.x) + fabsf(a.y) + fabsf(a.z) + fabsf(a.w);
    s2z += a.x * a.x + a.y * a.y + a.z * a.z + a.w * a.w;
    const float dx = a.x - c.x, dy = a.y - c.y, dz = a.z - c.z, dw = a.w - c.w;
    l1p += fabsf(dx) + fabsf(dy) + fabsf(dz) + fabsf(dw);
    s2p += dx * dx + dy * dy + dz * dz + dw * dw;
}

// ---------------------------------------------------------------------------
// Fused kernel (exact R7).
// Param path (blocks [0,640)): block-contiguous chunks; per chunk 3 bursts of
// {16 ascending 1 KB wave-lines from p (one 64 KB nt run), matching 64 KB
// from q consumed in groups of 4 (q issue order also one ascending run)}.
// Logits path: blocks [640, 1152): one block per batch row, row staged in LDS,
// log-sum-exp + CE/hinge/KL/entropy/energy partials, 5 atomics per block.
// ---------------------------------------------------------------------------
__global__ __launch_bounds__(256, 2) void fused_kernel(
        const float* __restrict__ p, const float* __restrict__ q,
        const float* __restrict__ outlog, const int* __restrict__ tgt,
        float* __restrict__ ws) {
    __shared__ float row[CC];
    __shared__ float scratch[4];

    const int bid = blockIdx.x;
    const int tid = (int)threadIdx.x;
    if (bid < PBLKS) {
        // ---------------- param-norm path (256 MB total) -------------------
        const int t = bid / BPT;
        const f32x4* __restrict__ pb = (const f32x4*)p + (long long)bid * C4;
        const f32x4* __restrict__ qb = (const f32x4*)q + (long long)bid * C4;

        float l1z = 0.f, s2z = 0.f, l1p = 0.f, s2p = 0.f;

        #pragma unroll 1
        for (int j = 0; j < 3; ++j) {
            const f32x4* bp = pb + j * 4096 + tid;
            const f32x4* bq = qb + j * 4096 + tid;
            f32x4 A[16];
            #pragma unroll
            for (int k = 0; k < 16; ++k) A[k] = ntload(bp + k * 256);
            #pragma unroll
            for (int g = 0; g < 4; ++g) {
                f32x4 Cg[4];
                #pragma unroll
                for (int k = 0; k < 4; ++k) Cg[k] = ntload(bq + (g * 4 + k) * 256);
                #pragma unroll
                for (int k = 0; k < 4; ++k)
                    acc4(A[g * 4 + k], Cg[k], l1z, s2z, l1p, s2p);
            }
        }
        // tail: 212 float4 at chunk offset 12288 (212 < 256: single pass OK)
        if (tid < TAIL4) {
            const f32x4 a = ntload(pb + 3 * 4096 + tid);
            const f32x4 c = ntload(qb + 3 * 4096 + tid);
            acc4(a, c, l1z, s2z, l1p, s2p);
        }

        for (int o = 32; o > 0; o >>= 1) {
            l1z += __shfl_down(l1z, o);
            s2z += __shfl_down(s2z, o);
            l1p += __shfl_down(l1p, o);
            s2p += __shfl_down(s2p, o);
        }
        if ((tid & 63) == 0) {
            float* base = ws + 8 + t * 4;
            atomicAdd(base + 0, l1z);
            atomicAdd(base + 1, s2z);
            atomicAdd(base + 2, l1p);
            atomicAdd(base + 3, s2p);
        }
    } else {
        // ---------------- logits path (one block per batch row) ------------
        const int b = bid - PBLKS;
        const float* __restrict__ o = outlog + (long long)b * CC;

        float sq = 0.f;
        for (int j = tid; j < CC; j += 256) {
            const float v = o[j];
            row[j] = v;
            sq += v * v;
        }
        __syncthreads();

        float m = -3.402823466e+38f;
        for (int j = tid; j < CC; j += 256) m = fmaxf(m, row[j]);
        m = block_reduce_max(m, scratch);

        float se = 0.f;
        for (int j = tid; j < CC; j += 256) se += __expf(row[j] - m);
        se = block_reduce_sum(se, scratch);
        const float logZ = m + __logf(se);

        const int tg = tgt[b];
        const float ot = row[tg];

        float ent = 0.f, lps = 0.f, hin = 0.f;
        for (int j = tid; j < CC; j += 256) {
            const float lp = row[j] - logZ;
            ent += __expf(lp) * lp;
            lps += lp;
            const float mg = 1.f - ot + row[j];
            if (j != tg && mg > 0.f) hin += mg;
        }
        sq  = block_reduce_sum(sq, scratch);
        ent = block_reduce_sum(ent, scratch);
        lps = block_reduce_sum(lps, scratch);
        hin = block_reduce_sum(hin, scratch);

        if (tid == 0) {
            atomicAdd(&ws[0], -(ot - logZ));
            atomicAdd(&ws[1], hin);
            atomicAdd(&ws[2], lps);
            atomicAdd(&ws[3], ent);
            atomicAdd(&ws[4], sq);
        }
    }
}

// ---------------------------------------------------------------------------
// Final combine — 64x9 sigmoid-weighted sum, one block
// ---------------------------------------------------------------------------
__global__ __launch_bounds__(256) void final_kernel(
        const float* __restrict__ lw, const float* __restrict__ ws,
        float* __restrict__ out) {
    __shared__ float scratch[4];
    const float ce      = ws[0] / (float)BB;
    const float hinge   = ws[1] / ((float)BB * (float)CC);
    const float kl      = -logf((float)CC) - ws[2] / ((float)BB * (float)CC);
    const float entropy = -ws[3] / (float)BB;
    const float energy  = sqrtf(ws[4]);
    const float glob[5] = {ce, hinge, kl, entropy, energy};

    float acc = 0.f;
    for (int i = threadIdx.x; i < TT * NW; i += 256) {
        const int t = i / NW;
        const int k = i - t * NW;
        float cmb;
        if (k < 5)       cmb = glob[k];
        else if (k == 5) cmb = ws[8 + t * 4 + 0];
        else if (k == 6) cmb = sqrtf(ws[8 + t * 4 + 1]);
        else if (k == 7) cmb = ws[8 + t * 4 + 2];
        else             cmb = sqrtf(ws[8 + t * 4 + 3]);
        const float w = 1.f / (1.f + expf(-lw[i]));
        acc += w * cmb;
    }
    acc = block_reduce_sum(acc, scratch);
    if (threadIdx.x == 0) out[0] = acc / (float)(TT * NW);
}

// ---------------------------------------------------------------------------
extern "C" void kernel_launch(void* const* d_in, const int* in_sizes, int n_in,
                              void* d_out, int out_size, void* d_ws, size_t ws_size,
                              hipStream_t stream) {
    const float* outputs    = (const float*)d_in[0];
    const int*   targets    = (const int*)d_in[1];
    const float* params     = (const float*)d_in[2];
    const float* pretrained = (const float*)d_in[3];
    const float* lw         = (const float*)d_in[4];
    float* ws  = (float*)d_ws;
    float* out = (float*)d_out;

    hipMemsetAsync(ws, 0, WS_FLOATS * sizeof(float), stream);

    // 640 param blocks (64 KB nt runs) + 512 logits blocks
    fused_kernel<<<PBLKS + BB, 256, 0, stream>>>(params, pretrained, outputs, targets, ws);
    final_kernel<<<1, 256, 0, stream>>>(lw, ws, out);
}